// Round 1
// baseline (100.652 us; speedup 1.0000x reference)
//
#include <hip/hip_runtime.h>

// BoxFilter: out = 9x9 box SUM of x with zero padding (truncated edge windows).
// Derivation: diff_x(cumsum_H(x), r) == vertical box-sum of width 2r+1 with
// truncated (== zero-padded) windows; then cumsum_W + diff_y == horizontal
// box-sum. r = 4 (fixed by setup_inputs).

#define RR 4
#define HH 1024
#define WW 1024
#define BLOCK 256
#define ROWS_PER_TILE 64
#define GROUP 8
#define LDSW (WW + 2 * RR) // 1032 floats per LDS row (4-col zero halo each side)

__global__ __launch_bounds__(BLOCK) void box9_kernel(const float* __restrict__ x,
                                                     float* __restrict__ out) {
    const int tid  = threadIdx.x;
    const int img  = blockIdx.y;
    const int row0 = blockIdx.x * ROWS_PER_TILE;
    const size_t ioff = (size_t)img * HH * WW;
    const float* __restrict__ xi = x + ioff;
    float* __restrict__ oi       = out + ioff;
    const int c = 4 * tid; // this thread's 4 columns: c .. c+3 (0..1023 exactly)

    __shared__ float vlds[GROUP][LDSW];

    // Constant-zero column halos (cols -4..-1 -> lds 0..3, cols 1024..1027 -> lds 1028..1031).
    // Written once; never overwritten by the group loop.
    if (tid < GROUP) {
        vlds[tid][0] = 0.f; vlds[tid][1] = 0.f; vlds[tid][2] = 0.f; vlds[tid][3] = 0.f;
        vlds[tid][LDSW - 4] = 0.f; vlds[tid][LDSW - 3] = 0.f;
        vlds[tid][LDSW - 2] = 0.f; vlds[tid][LDSW - 1] = 0.f;
    }

    // Vertical window init: v = sum of rows row0-4 .. row0+4 (zero outside image).
    // All row-bound branches are block-uniform (no lane divergence anywhere).
    float4 v; v.x = 0.f; v.y = 0.f; v.z = 0.f; v.w = 0.f;
#pragma unroll
    for (int k = 0; k < 2 * RR + 1; ++k) {
        const int rr = row0 - RR + k;
        if (rr >= 0 && rr < HH) {
            const float4 t = *reinterpret_cast<const float4*>(xi + (size_t)rr * WW + c);
            v.x += t.x; v.y += t.y; v.z += t.z; v.w += t.w;
        }
    }

    for (int g = 0; g < ROWS_PER_TILE / GROUP; ++g) {
        const int base = row0 + g * GROUP;
        // Phase 1: publish v-rows (vertical box sums) for this 8-row group.
#pragma unroll
        for (int k = 0; k < GROUP; ++k) {
            const int i = base + k;
            *reinterpret_cast<float4*>(&vlds[k][4 + c]) = v;
            // Advance v to row i+1: add row i+5, drop row i-4.
            const int rn = i + RR + 1;
            const int rd = i - RR;
            float4 nv; nv.x = 0.f; nv.y = 0.f; nv.z = 0.f; nv.w = 0.f;
            float4 dv; dv.x = 0.f; dv.y = 0.f; dv.z = 0.f; dv.w = 0.f;
            if (rn < HH) nv = *reinterpret_cast<const float4*>(xi + (size_t)rn * WW + c);
            if (rd >= 0) dv = *reinterpret_cast<const float4*>(xi + (size_t)rd * WW + c);
            v.x += nv.x - dv.x; v.y += nv.y - dv.y;
            v.z += nv.z - dv.z; v.w += nv.w - dv.w;
        }
        __syncthreads();
        // Phase 2: horizontal 9-tap sliding sum from LDS, 4 outputs/thread.
#pragma unroll
        for (int k = 0; k < GROUP; ++k) {
            const int i = base + k;
            const float4 a0 = *reinterpret_cast<const float4*>(&vlds[k][c]);
            const float4 a1 = *reinterpret_cast<const float4*>(&vlds[k][c + 4]);
            const float4 a2 = *reinterpret_cast<const float4*>(&vlds[k][c + 8]);
            float s = a0.x + a0.y + a0.z + a0.w + a1.x + a1.y + a1.z + a1.w + a2.x;
            float4 o;
            o.x = s;
            s += a2.y - a0.x; o.y = s;
            s += a2.z - a0.y; o.z = s;
            s += a2.w - a0.z; o.w = s;
            *reinterpret_cast<float4*>(oi + (size_t)i * WW + c) = o;
        }
        __syncthreads();
    }
}

extern "C" void kernel_launch(void* const* d_in, const int* in_sizes, int n_in,
                              void* d_out, int out_size, void* d_ws, size_t ws_size,
                              hipStream_t stream) {
    const float* x = (const float*)d_in[0];
    float* out     = (float*)d_out;
    const int nimg = in_sizes[0] / (HH * WW); // 48 images (16 batch x 3 channels)
    dim3 grid(HH / ROWS_PER_TILE, nimg, 1);   // (16, 48)
    box9_kernel<<<grid, BLOCK, 0, stream>>>(x, out);
}